// Round 1
// baseline (314.976 us; speedup 1.0000x reference)
//
#include <hip/hip_runtime.h>
#include <hip/hip_bf16.h>
#include <cstdint>
#include <cstddef>

// YatAttention on MI355X (gfx950).
// B=2, L=2048, E=768, H=12, D=64. All GEMM-shaped compute in bf16 MFMA
// 16x16x32 (fp32 accum); score transform + softmax in fp32.
// Verified layouts (learn_hip m89/m91): C/D col=lane&15, row=(lane>>4)*4+reg;
// A-operand m=lane&15, k=(lane>>4)*8+j; B-operand n=lane&15, k=(lane>>4)*8+j.

typedef __bf16 bf16_t;
typedef __bf16 bf16x8 __attribute__((ext_vector_type(8)));
typedef __bf16 bf16x4 __attribute__((ext_vector_type(4)));
typedef float floatx4 __attribute__((ext_vector_type(4)));

#define DEVI static __device__ __forceinline__

#define Bc 2
#define Lc 2048
#define Ec 768
#define Hc 12
#define Dc 64
#define N3c 2304
#define Mc 4096

DEVI void glds16(const bf16_t* g, bf16_t* l) {
  __builtin_amdgcn_global_load_lds(
      (const __attribute__((address_space(1))) void*)g,
      (__attribute__((address_space(3))) void*)l, 16, 0, 0);
}

// ---------------- conversion kernels ----------------

__global__ __launch_bounds__(256) void k_cvt(const float* __restrict__ in,
                                             bf16_t* __restrict__ out, int n) {
  int i = (blockIdx.x * 256 + threadIdx.x) * 4;
  if (i >= n) return;
  float4 v = *(const float4*)(in + i);
  bf16x4 o;
  o[0] = (bf16_t)v.x; o[1] = (bf16_t)v.y; o[2] = (bf16_t)v.z; o[3] = (bf16_t)v.w;
  *(bf16x4*)(out + i) = o;
}

// in: R x C fp32 row-major  ->  out: C x R bf16 row-major (i.e. in^T)
__global__ __launch_bounds__(256) void k_tc(const float* __restrict__ in,
                                            bf16_t* __restrict__ out, int R, int C) {
  __shared__ float tile[32][33];
  int c0 = blockIdx.x * 32, r0 = blockIdx.y * 32;
  int tx = threadIdx.x, ty = threadIdx.y;
  #pragma unroll
  for (int i = 0; i < 32; i += 8)
    tile[ty + i][tx] = in[(size_t)(r0 + ty + i) * C + c0 + tx];
  __syncthreads();
  #pragma unroll
  for (int i = 0; i < 32; i += 8)
    out[(size_t)(c0 + ty + i) * R + r0 + tx] = (bf16_t)tile[tx][ty + i];
}

// ---------------- GEMM core (m97 pattern) ----------------
// C[128x128] per block, 4 waves in 2x2, each wave 64x64 as 4x4 16x16 frags.
// A: (M x 768) bf16 row-major. Bt: (N x 768) bf16 row-major (= B^T). K=768.

DEVI void gemm_core(const bf16_t* __restrict__ A, const bf16_t* __restrict__ Bt,
                    bf16_t* lA, bf16_t* lB, int m0, int n0, floatx4 (&acc)[4][4]) {
  const int tid = threadIdx.x, wave = tid >> 6, lane = tid & 63;
  const int wm = (wave >> 1) * 64, wn = (wave & 1) * 64;
  const int lrow = lane >> 2, lseg = lane & 3;
  const int quad = lane >> 4, r16 = lane & 15;
  for (int kk = 0; kk < 768; kk += 32) {
    glds16(A  + (size_t)(m0 + wave * 32      + lrow) * 768 + kk + lseg * 8, lA + (wave * 32) * 32);
    glds16(A  + (size_t)(m0 + wave * 32 + 16 + lrow) * 768 + kk + lseg * 8, lA + (wave * 32 + 16) * 32);
    glds16(Bt + (size_t)(n0 + wave * 32      + lrow) * 768 + kk + lseg * 8, lB + (wave * 32) * 32);
    glds16(Bt + (size_t)(n0 + wave * 32 + 16 + lrow) * 768 + kk + lseg * 8, lB + (wave * 32 + 16) * 32);
    __syncthreads();
    bf16x8 af[4], bv[4];
    #pragma unroll
    for (int mi = 0; mi < 4; mi++)
      af[mi] = *(const bf16x8*)(lA + (wm + mi * 16 + r16) * 32 + quad * 8);
    #pragma unroll
    for (int ni = 0; ni < 4; ni++)
      bv[ni] = *(const bf16x8*)(lB + (wn + ni * 16 + r16) * 32 + quad * 8);
    #pragma unroll
    for (int mi = 0; mi < 4; mi++)
      #pragma unroll
      for (int ni = 0; ni < 4; ni++)
        acc[mi][ni] = __builtin_amdgcn_mfma_f32_16x16x32_bf16(af[mi], bv[ni], acc[mi][ni], 0, 0, 0);
    __syncthreads();
  }
}

// QKV GEMM: C = xb @ WqkvT^T + bqkv, scattered into Q/K/V (B,H,L,D) bf16.
__global__ __launch_bounds__(256) void k_gemm_qkv(
    const bf16_t* __restrict__ A, const bf16_t* __restrict__ Bt,
    const float* __restrict__ bias,
    bf16_t* __restrict__ Qo, bf16_t* __restrict__ Ko, bf16_t* __restrict__ Vo) {
  __shared__ bf16_t lA[128 * 32];
  __shared__ bf16_t lB[128 * 32];
  const int m0 = blockIdx.y * 128, n0 = blockIdx.x * 128;
  const int tid = threadIdx.x, wave = tid >> 6, lane = tid & 63;
  const int wm = (wave >> 1) * 64, wn = (wave & 1) * 64;
  const int quad = lane >> 4, r16 = lane & 15;
  floatx4 acc[4][4] = {};
  gemm_core(A, Bt, lA, lB, m0, n0, acc);

  const int sec = n0 / 768;  // block-uniform (768 % 128 tile boundary safe: 6 tiles/section)
  bf16_t* dst = (sec == 0) ? Qo : ((sec == 1) ? Ko : Vo);
  #pragma unroll
  for (int ni = 0; ni < 4; ni++) {
    const int n = n0 + wn + ni * 16 + r16;
    const int nn = n - sec * 768;
    const int h = nn >> 6, d = nn & 63;
    const float bvs = bias[n];
    #pragma unroll
    for (int mi = 0; mi < 4; mi++) {
      #pragma unroll
      for (int reg = 0; reg < 4; reg++) {
        const int m = m0 + wm + mi * 16 + quad * 4 + reg;
        const int b = m >> 11, l = m & 2047;
        const float v = acc[mi][ni][reg] + bvs;
        dst[(((size_t)(b * Hc + h)) * Lc + l) * Dc + d] = (bf16_t)v;
      }
    }
  }
}

// Output projection: out = AO @ WoutT^T + bout (fp32 out).
__global__ __launch_bounds__(256) void k_gemm_out(
    const bf16_t* __restrict__ A, const bf16_t* __restrict__ Bt,
    const float* __restrict__ bias, float* __restrict__ out) {
  __shared__ bf16_t lA[128 * 32];
  __shared__ bf16_t lB[128 * 32];
  const int m0 = blockIdx.y * 128, n0 = blockIdx.x * 128;
  const int tid = threadIdx.x, wave = tid >> 6, lane = tid & 63;
  const int wm = (wave >> 1) * 64, wn = (wave & 1) * 64;
  const int quad = lane >> 4, r16 = lane & 15;
  floatx4 acc[4][4] = {};
  gemm_core(A, Bt, lA, lB, m0, n0, acc);
  #pragma unroll
  for (int ni = 0; ni < 4; ni++) {
    const int n = n0 + wn + ni * 16 + r16;
    const float bvs = bias[n];
    #pragma unroll
    for (int mi = 0; mi < 4; mi++) {
      #pragma unroll
      for (int reg = 0; reg < 4; reg++) {
        const int m = m0 + wm + mi * 16 + quad * 4 + reg;
        out[(size_t)m * Ec + n] = acc[mi][ni][reg] + bvs;
      }
    }
  }
}

// ---------------- q_sq / k_sq (from bf16-rounded q,k for consistency) ----------------
__global__ __launch_bounds__(256) void k_sq(const bf16_t* __restrict__ Q,
                                            const bf16_t* __restrict__ K,
                                            float* __restrict__ qsq, float* __restrict__ ksq) {
  const int row = blockIdx.x * 256 + threadIdx.x;  // < 24*2048
  const bf16x8* q = (const bf16x8*)(Q + (size_t)row * 64);
  const bf16x8* k = (const bf16x8*)(K + (size_t)row * 64);
  float sq = 0.f, sk = 0.f;
  #pragma unroll
  for (int c = 0; c < 8; c++) {
    bf16x8 vq = q[c], vk = k[c];
    #pragma unroll
    for (int j = 0; j < 8; j++) {
      float a = (float)vq[j]; sq += a * a;
      float b = (float)vk[j]; sk += b * b;
    }
  }
  qsq[row] = sq;
  ksq[row] = sk;
}

// ---------------- V transpose: (B,H,L,D) -> (B,H,D,L) ----------------
__global__ __launch_bounds__(256) void k_vt(const bf16_t* __restrict__ V,
                                            bf16_t* __restrict__ VT) {
  __shared__ bf16_t t[64][72];  // pad to 72 (144B rows, 16B aligned)
  const int gid = blockIdx.x;   // 24 * 32
  const int bh = gid >> 5, j0 = (gid & 31) * 64;
  const int tid = threadIdx.x;
  const bf16_t* Vh = V + ((size_t)bh * Lc) * Dc;
  bf16_t* VTh = VT + ((size_t)bh * Dc) * Lc;
  #pragma unroll
  for (int it = 0; it < 2; ++it) {
    int c = tid + it * 256;  // 0..511 chunk of 16B
    int j = c >> 3, seg = c & 7;
    *(bf16x8*)&t[j][seg * 8] = *(const bf16x8*)(Vh + (size_t)(j0 + j) * 64 + seg * 8);
  }
  __syncthreads();
  #pragma unroll
  for (int it = 0; it < 2; ++it) {
    int c = tid + it * 256;
    int d = c >> 3, jseg = c & 7;
    bf16x8 o;
    #pragma unroll
    for (int u = 0; u < 8; u++) o[u] = t[jseg * 8 + u][d];
    *(bf16x8*)(VTh + (size_t)d * Lc + j0 + jseg * 8) = o;
  }
}

// ---------------- flash attention with Yat score transform ----------------
// grid = 24*32 blocks; block = 4 waves; wave handles 16 q-rows; key tile = 64.
__global__ __launch_bounds__(256) void k_attn(
    const bf16_t* __restrict__ Q, const bf16_t* __restrict__ K,
    const bf16_t* __restrict__ VT, const float* __restrict__ qsq,
    const float* __restrict__ ksq, const int* __restrict__ mask,
    bf16_t* __restrict__ AO) {
  __shared__ bf16_t lP[4][16 * 72];  // per-wave P staging, stride 72 (16B-aligned rows)
  const int gid = blockIdx.x;
  const int bh = gid >> 5, qt = gid & 31;
  const int b = bh / Hc, h = bh - b * Hc;
  const int tid = threadIdx.x, wave = tid >> 6, lane = tid & 63;
  const int quad = lane >> 4, r16 = lane & 15;
  const int q0 = qt * 64 + wave * 16;
  const bf16_t* Qh = Q + ((size_t)bh * Lc) * Dc;
  const bf16_t* Kh = K + ((size_t)bh * Lc) * Dc;
  const bf16_t* VTh = VT + ((size_t)bh * Dc) * Lc;
  const float* qsqh = qsq + bh * Lc;
  const float* ksqh = ksq + bh * Lc;
  const int* maskb = mask + b * Lc;
  bf16_t* myP = &lP[wave][0];

  // Q A-fragments (resident for the whole loop)
  bf16x8 qf0 = *(const bf16x8*)(Qh + (size_t)(q0 + r16) * 64 + quad * 8);
  bf16x8 qf1 = *(const bf16x8*)(Qh + (size_t)(q0 + r16) * 64 + 32 + quad * 8);
  float qs[4], mi[4], li[4];
  floatx4 of[4] = {};
  #pragma unroll
  for (int reg = 0; reg < 4; reg++) {
    qs[reg] = qsqh[q0 + quad * 4 + reg];
    mi[reg] = -1e30f;
    li[reg] = 0.f;
  }

  for (int kt = 0; kt < Lc; kt += 64) {
    floatx4 dot[4];
    float ksv[4], mkv[4];
    #pragma unroll
    for (int c = 0; c < 4; c++) {
      const int col = kt + c * 16 + r16;
      ksv[c] = ksqh[col];
      mkv[c] = (maskb[col] == 1) ? 1.f : 0.f;
      bf16x8 kf0 = *(const bf16x8*)(Kh + (size_t)col * 64 + quad * 8);
      bf16x8 kf1 = *(const bf16x8*)(Kh + (size_t)col * 64 + 32 + quad * 8);
      floatx4 a = {};
      a = __builtin_amdgcn_mfma_f32_16x16x32_bf16(qf0, kf0, a, 0, 0, 0);
      a = __builtin_amdgcn_mfma_f32_16x16x32_bf16(qf1, kf1, a, 0, 0, 0);
      dot[c] = a;
    }
    #pragma unroll
    for (int reg = 0; reg < 4; reg++) {
      float sv[4];
      float rmax = -1e30f;
      #pragma unroll
      for (int c = 0; c < 4; c++) {
        const float dd = dot[c][reg];
        const float den = qs[reg] + ksv[c] - 2.f * dd + 1e-6f;
        float sc = dd * dd * __builtin_amdgcn_rcpf(den);  // scores >= 0
        sc = (mkv[c] != 0.f) ? sc : -1e30f;
        sv[c] = sc;
        rmax = fmaxf(rmax, sc);
      }
      rmax = fmaxf(rmax, __shfl_xor(rmax, 1, 16));
      rmax = fmaxf(rmax, __shfl_xor(rmax, 2, 16));
      rmax = fmaxf(rmax, __shfl_xor(rmax, 4, 16));
      rmax = fmaxf(rmax, __shfl_xor(rmax, 8, 16));
      const float mnew = fmaxf(mi[reg], rmax);
      const float alpha = __expf(mi[reg] - mnew);
      float psum = 0.f;
      #pragma unroll
      for (int c = 0; c < 4; c++) {
        const float p = (mkv[c] != 0.f) ? __expf(sv[c] - mnew) : 0.f;
        psum += p;
        myP[(quad * 4 + reg) * 72 + c * 16 + r16] = (bf16_t)p;  // C-layout -> LDS
      }
      psum += __shfl_xor(psum, 1, 16);
      psum += __shfl_xor(psum, 2, 16);
      psum += __shfl_xor(psum, 4, 16);
      psum += __shfl_xor(psum, 8, 16);
      li[reg] = li[reg] * alpha + psum;
      mi[reg] = mnew;
      #pragma unroll
      for (int t4 = 0; t4 < 4; t4++) of[t4][reg] *= alpha;
    }
    // P: LDS C-layout -> A-operand fragments (same-wave DS ops are in-order)
    bf16x8 pf0 = *(const bf16x8*)(myP + r16 * 72 + quad * 8);
    bf16x8 pf1 = *(const bf16x8*)(myP + r16 * 72 + 32 + quad * 8);
    #pragma unroll
    for (int t4 = 0; t4 < 4; t4++) {
      bf16x8 vf0 = *(const bf16x8*)(VTh + (size_t)(t4 * 16 + r16) * Lc + kt + quad * 8);
      bf16x8 vf1 = *(const bf16x8*)(VTh + (size_t)(t4 * 16 + r16) * Lc + kt + 32 + quad * 8);
      of[t4] = __builtin_amdgcn_mfma_f32_16x16x32_bf16(pf0, vf0, of[t4], 0, 0, 0);
      of[t4] = __builtin_amdgcn_mfma_f32_16x16x32_bf16(pf1, vf1, of[t4], 0, 0, 0);
    }
  }
  #pragma unroll
  for (int reg = 0; reg < 4; reg++) {
    const float inv = (li[reg] > 0.f) ? __builtin_amdgcn_rcpf(li[reg]) : 0.f;
    const int l = q0 + quad * 4 + reg;
    #pragma unroll
    for (int t4 = 0; t4 < 4; t4++) {
      const float v = of[t4][reg] * inv;
      AO[((size_t)(b * Lc + l)) * Ec + h * 64 + t4 * 16 + r16] = (bf16_t)v;
    }
  }
}

// ---------------- launch ----------------

extern "C" void kernel_launch(void* const* d_in, const int* in_sizes, int n_in,
                              void* d_out, int out_size, void* d_ws, size_t ws_size,
                              hipStream_t stream) {
  const float* x    = (const float*)d_in[0];
  const int*   mask = (const int*)d_in[1];
  const float* Wqkv = (const float*)d_in[2];
  const float* bqkv = (const float*)d_in[3];
  const float* Wout = (const float*)d_in[4];
  const float* bout = (const float*)d_in[5];
  float* out = (float*)d_out;

  char* ws = (char*)d_ws;
  size_t off = 0;
  auto carve = [&](size_t bytes) -> char* {
    char* p = ws + off;
    off += (bytes + 255) & ~(size_t)255;
    return p;
  };
  bf16_t* xb  = (bf16_t*)carve((size_t)Mc * Ec * 2);       // also reused as AO
  bf16_t* WqT = (bf16_t*)carve((size_t)N3c * Ec * 2);
  bf16_t* WoT = (bf16_t*)carve((size_t)Ec * Ec * 2);
  bf16_t* Qb  = (bf16_t*)carve((size_t)Bc * Hc * Lc * Dc * 2);
  bf16_t* Kb  = (bf16_t*)carve((size_t)Bc * Hc * Lc * Dc * 2);
  bf16_t* Vb  = (bf16_t*)carve((size_t)Bc * Hc * Lc * Dc * 2);
  bf16_t* VTb = (bf16_t*)carve((size_t)Bc * Hc * Lc * Dc * 2);
  bf16_t* AOb = (bf16_t*)carve((size_t)Mc * Ec * 2);
  float*  qsq = (float*)carve((size_t)Bc * Hc * Lc * 4);
  float*  ksq = (float*)carve((size_t)Bc * Hc * Lc * 4);
  (void)in_sizes; (void)n_in; (void)out_size; (void)ws_size;

  k_cvt<<<(Mc * Ec / 4 + 255) / 256, 256, 0, stream>>>(x, xb, Mc * Ec);
  k_tc<<<dim3(N3c / 32, Ec / 32), dim3(32, 8), 0, stream>>>(Wqkv, WqT, Ec, N3c);
  k_tc<<<dim3(Ec / 32, Ec / 32), dim3(32, 8), 0, stream>>>(Wout, WoT, Ec, Ec);
  k_gemm_qkv<<<dim3(N3c / 128, Mc / 128), 256, 0, stream>>>(xb, WqT, bqkv, Qb, Kb, Vb);
  k_sq<<<Bc * Hc * Lc / 256, 256, 0, stream>>>(Qb, Kb, qsq, ksq);
  k_vt<<<Bc * Hc * Lc / 64, 256, 0, stream>>>(Vb, VTb);
  k_attn<<<Bc * Hc * Lc / 64, 256, 0, stream>>>(Qb, Kb, VTb, qsq, ksq, mask, AOb);
  k_gemm_out<<<dim3(Ec / 128, Mc / 128), 256, 0, stream>>>(AOb, WoT, bout, out);
}